// Round 1
// baseline (191.527 us; speedup 1.0000x reference)
//
#include <hip/hip_runtime.h>
#include <math.h>

typedef __attribute__((ext_vector_type(8))) short bf16x8;
typedef __attribute__((ext_vector_type(4))) float f32x4;

#define PI_F 3.14159265358979323846f

__device__ __forceinline__ unsigned short f2bf(float f) {
  unsigned int u = __float_as_uint(f);
  u += 0x7FFFu + ((u >> 16) & 1u);   // RNE to bf16
  return (unsigned short)(u >> 16);
}

__device__ __forceinline__ void async_ld16(const unsigned short* g, unsigned short* l) {
  __builtin_amdgcn_global_load_lds(
      (const __attribute__((address_space(1))) void*)g,
      (__attribute__((address_space(3))) void*)l,
      16, 0, 0);
}

// ---------------- fp32 -> bf16 convert (vectorized x4) ----------------
__global__ __launch_bounds__(256)
void cvt_bf16_kernel(const float* __restrict__ s, unsigned short* __restrict__ d, int n4) {
  int i = blockIdx.x * 256 + threadIdx.x;
  if (i < n4) {
    float4 v = ((const float4*)s)[i];
    ushort4 o;
    o.x = f2bf(v.x); o.y = f2bf(v.y); o.z = f2bf(v.z); o.w = f2bf(v.w);
    ((ushort4*)d)[i] = o;
  }
}

// ---------------- transpose + convert: x (16,1024,256) -> xT (16,256,1024) bf16 ----------------
__global__ __launch_bounds__(256)
void transpose_cvt_kernel(const float* __restrict__ x, unsigned short* __restrict__ xT) {
  __shared__ float tile[32][33];
  int jt = blockIdx.x;   // 0..31  (1024/32)
  int ht = blockIdx.y;   // 0..7   (256/32)
  int b  = blockIdx.z;   // 0..15
  int tx = threadIdx.x;  // 0..31
  int ty = threadIdx.y;  // 0..7
  const float* xb = x + (size_t)b * 1024 * 256;
  #pragma unroll
  for (int i = 0; i < 4; i++) {
    int j = jt * 32 + ty + i * 8;
    tile[ty + i * 8][tx] = xb[(size_t)j * 256 + ht * 32 + tx];
  }
  __syncthreads();
  unsigned short* xTb = xT + (size_t)b * 256 * 1024;
  #pragma unroll
  for (int i = 0; i < 4; i++) {
    int h = ht * 32 + ty + i * 8;
    xTb[(size_t)h * 1024 + jt * 32 + tx] = f2bf(tile[tx][ty + i * 8]);
  }
}

// ---------------- MFMA GEMM, C = A * Bt^T  (A: MxK row-major bf16, Bt: NxK row-major bf16) ----
// MODE 0: store bf16 C.  MODE 1: bias + exact GELU, store fp32 C.
template<int MODE>
__global__ __launch_bounds__(256)
void gemm_bt_kernel(const unsigned short* __restrict__ A,
                    const unsigned short* __restrict__ Bt,
                    void* __restrict__ C,
                    const float* __restrict__ bias,
                    int K, int tilesM, int tilesN,
                    long long strideA, long long strideBt, long long strideC, int ldC) {
  __shared__ unsigned short As[128 * 32];
  __shared__ unsigned short Bs[128 * 32];
  int tiles = tilesM * tilesN;
  int b   = blockIdx.x / tiles;
  int rr  = blockIdx.x % tiles;
  int im  = rr / tilesN;
  int in_ = rr % tilesN;
  const unsigned short* Ab  = A  + (long long)b * strideA  + (long long)im * 128 * K;
  const unsigned short* Btb = Bt + (long long)b * strideBt + (long long)in_ * 128 * K;

  int t = threadIdx.x;
  int wv = t >> 6, lane = t & 63;
  int wm = wv >> 1, wn = wv & 1;
  int l15 = lane & 15, quad = lane >> 4;
  int row0 = t >> 2, cg = t & 3;

  f32x4 acc[4][4] = {};

  for (int kk = 0; kk < K; kk += 32) {
    __syncthreads();
    #pragma unroll
    for (int q = 0; q < 2; q++) {
      int row = row0 + q * 64;
      const unsigned short* ga = Ab  + (long long)row * K + kk + cg * 8;
      const unsigned short* gb = Btb + (long long)row * K + kk + cg * 8;
      unsigned short* la = &As[(wv * 64 + q * 256) * 8];
      unsigned short* lb = &Bs[(wv * 64 + q * 256) * 8];
      async_ld16(ga, la);
      async_ld16(gb, lb);
    }
    __syncthreads();
    bf16x8 af[4], bfr[4];
    #pragma unroll
    for (int mt = 0; mt < 4; mt++)
      af[mt] = *(const bf16x8*)&As[(wm * 64 + mt * 16 + l15) * 32 + quad * 8];
    #pragma unroll
    for (int nt = 0; nt < 4; nt++)
      bfr[nt] = *(const bf16x8*)&Bs[(wn * 64 + nt * 16 + l15) * 32 + quad * 8];
    #pragma unroll
    for (int mt = 0; mt < 4; mt++)
      #pragma unroll
      for (int nt = 0; nt < 4; nt++)
        acc[mt][nt] = __builtin_amdgcn_mfma_f32_16x16x32_bf16(af[mt], bfr[nt], acc[mt][nt], 0, 0, 0);
  }

  unsigned short* Cb_bf = (unsigned short*)C + (long long)b * strideC;
  float*          Cb_f  = (float*)C          + (long long)b * strideC;
  int n0 = in_ * 128;
  #pragma unroll
  for (int mt = 0; mt < 4; mt++) {
    #pragma unroll
    for (int nt = 0; nt < 4; nt++) {
      int colg = n0 + wn * 64 + nt * 16 + l15;
      #pragma unroll
      for (int r = 0; r < 4; r++) {
        long long rowg = (long long)im * 128 + wm * 64 + mt * 16 + quad * 4 + r;
        float v = acc[mt][nt][r];
        if (MODE == 0) {
          Cb_bf[rowg * ldC + colg] = f2bf(v);
        } else {
          v += bias[colg];
          v = 0.5f * v * (1.0f + erff(v * 0.7071067811865475f));
          Cb_f[rowg * ldC + colg] = v;
        }
      }
    }
  }
}

// ---------------- fused: angles -> 8-qubit circuit -> <Z> -> Wpost epilogue ----------------
// one sample per wave; 256 amplitudes = 4 complex per lane.
// amp index k: bits 0..5 = lane, bits 6..7 = register r (k = r*64 + lane).
__global__ __launch_bounds__(256)
void qcircuit_kernel(const float* __restrict__ g,
                     const float* __restrict__ Wpre, const float* __restrict__ bpre,
                     const float* __restrict__ qw,
                     const float* __restrict__ Wpost, const float* __restrict__ bpost,
                     float* __restrict__ out) {
  __shared__ float sWpre[2048];   // [w][h]  8x256
  __shared__ float sWpost[2048];  // [h][w]  256x8
  __shared__ float sBpost[256];
  int t = threadIdx.x;
  for (int i = t; i < 2048; i += 256) { sWpre[i] = Wpre[i]; sWpost[i] = Wpost[i]; }
  sBpost[t] = bpost[t];
  __syncthreads();

  int wv = t >> 6, L = t & 63;
  long long s = (long long)blockIdx.x * 4 + wv;
  const float* gr = g + s * 256;

  float gv[4];
  #pragma unroll
  for (int j = 0; j < 4; j++) gv[j] = gr[L + 64 * j];

  // angles: theta_w = tanh(g . Wpre[w] + bpre[w]) * pi
  float ang[8];
  #pragma unroll
  for (int w = 0; w < 8; w++) ang[w] = 0.f;
  #pragma unroll
  for (int j = 0; j < 4; j++)
    #pragma unroll
    for (int w = 0; w < 8; w++)
      ang[w] = fmaf(gv[j], sWpre[w * 256 + L + 64 * j], ang[w]);
  #pragma unroll
  for (int d = 1; d < 64; d <<= 1)
    #pragma unroll
    for (int w = 0; w < 8; w++)
      ang[w] += __shfl_xor(ang[w], d, 64);

  float cw[8], sw[8];
  #pragma unroll
  for (int w = 0; w < 8; w++) {
    float th = 0.5f * PI_F * tanhf(ang[w] + bpre[w]);  // half-angle of RY
    cw[w] = cosf(th); sw[w] = sinf(th);
  }

  // product state after RY embedding
  float re[4], im[4];
  #pragma unroll
  for (int r = 0; r < 4; r++) {
    int k = r * 64 + L;
    float v = 1.f;
    #pragma unroll
    for (int w = 0; w < 8; w++) v *= ((k >> w) & 1) ? sw[w] : cw[w];
    re[r] = v; im[r] = 0.f;
  }

  // 2 entangler layers: RX on all wires, then ring CNOT (0,1)..(7,0)
  #pragma unroll
  for (int l = 0; l < 2; l++) {
    #pragma unroll
    for (int w = 0; w < 6; w++) {           // RX cross-lane wires
      float hh = 0.5f * qw[l * 8 + w];
      float c = cosf(hh), sg = sinf(hh);
      #pragma unroll
      for (int r = 0; r < 4; r++) {
        float rp = __shfl_xor(re[r], 1 << w, 64);
        float ip = __shfl_xor(im[r], 1 << w, 64);
        re[r] = fmaf(c, re[r],  sg * ip);
        im[r] = fmaf(c, im[r], -sg * rp);
      }
    }
    {                                        // RX wire 6: reg pairs (0,1),(2,3)
      float hh = 0.5f * qw[l * 8 + 6];
      float c = cosf(hh), sg = sinf(hh);
      float r0 = re[0], i0 = im[0], r1 = re[1], i1 = im[1];
      float r2 = re[2], i2 = im[2], r3 = re[3], i3 = im[3];
      re[0] = fmaf(c, r0, sg * i1); im[0] = fmaf(c, i0, -sg * r1);
      re[1] = fmaf(c, r1, sg * i0); im[1] = fmaf(c, i1, -sg * r0);
      re[2] = fmaf(c, r2, sg * i3); im[2] = fmaf(c, i2, -sg * r3);
      re[3] = fmaf(c, r3, sg * i2); im[3] = fmaf(c, i3, -sg * r2);
    }
    {                                        // RX wire 7: reg pairs (0,2),(1,3)
      float hh = 0.5f * qw[l * 8 + 7];
      float c = cosf(hh), sg = sinf(hh);
      float r0 = re[0], i0 = im[0], r1 = re[1], i1 = im[1];
      float r2 = re[2], i2 = im[2], r3 = re[3], i3 = im[3];
      re[0] = fmaf(c, r0, sg * i2); im[0] = fmaf(c, i0, -sg * r2);
      re[2] = fmaf(c, r2, sg * i0); im[2] = fmaf(c, i2, -sg * r0);
      re[1] = fmaf(c, r1, sg * i3); im[1] = fmaf(c, i1, -sg * r3);
      re[3] = fmaf(c, r3, sg * i1); im[3] = fmaf(c, i3, -sg * r1);
    }
    #pragma unroll
    for (int cwire = 0; cwire < 5; cwire++) { // CNOT(c,c+1), c=0..4 (lane bits)
      int tw = cwire + 1;
      bool bc = (L >> cwire) & 1;
      #pragma unroll
      for (int r = 0; r < 4; r++) {
        float rp = __shfl_xor(re[r], 1 << tw, 64);
        float ip = __shfl_xor(im[r], 1 << tw, 64);
        re[r] = bc ? rp : re[r];
        im[r] = bc ? ip : im[r];
      }
    }
    {                                        // CNOT(5,6): lanes with bit5 swap r0<->r1, r2<->r3
      bool b5 = (L >> 5) & 1;
      float t0;
      t0 = re[0]; re[0] = b5 ? re[1] : re[0]; re[1] = b5 ? t0 : re[1];
      t0 = im[0]; im[0] = b5 ? im[1] : im[0]; im[1] = b5 ? t0 : im[1];
      t0 = re[2]; re[2] = b5 ? re[3] : re[2]; re[3] = b5 ? t0 : re[3];
      t0 = im[2]; im[2] = b5 ? im[3] : im[2]; im[3] = b5 ? t0 : im[3];
    }
    {                                        // CNOT(6,7): swap r1 <-> r3 (all lanes)
      float t0 = re[1]; re[1] = re[3]; re[3] = t0;
      t0 = im[1]; im[1] = im[3]; im[3] = t0;
    }
    {                                        // CNOT(7,0): r2,r3 swap across lane bit 0
      re[2] = __shfl_xor(re[2], 1, 64); im[2] = __shfl_xor(im[2], 1, 64);
      re[3] = __shfl_xor(re[3], 1, 64); im[3] = __shfl_xor(im[3], 1, 64);
    }
  }

  // measure <Z_w>
  float p0 = re[0] * re[0] + im[0] * im[0];
  float p1 = re[1] * re[1] + im[1] * im[1];
  float p2 = re[2] * re[2] + im[2] * im[2];
  float p3 = re[3] * re[3] + im[3] * im[3];
  float pt = p0 + p1 + p2 + p3;
  float z[8];
  #pragma unroll
  for (int w = 0; w < 6; w++) z[w] = ((L >> w) & 1) ? -pt : pt;
  z[6] = p0 - p1 + p2 - p3;   // bit6 = r&1
  z[7] = p0 + p1 - p2 - p3;   // bit7 = r>>1
  #pragma unroll
  for (int d = 1; d < 64; d <<= 1)
    #pragma unroll
    for (int w = 0; w < 8; w++)
      z[w] += __shfl_xor(z[w], d, 64);

  // out = z @ Wpost^T + bpost
  float* orow = out + s * 256;
  #pragma unroll
  for (int j = 0; j < 4; j++) {
    int hcol = L + 64 * j;
    float v = sBpost[hcol];
    #pragma unroll
    for (int w = 0; w < 8; w++) v = fmaf(z[w], sWpost[hcol * 8 + w], v);
    orow[hcol] = v;
  }
}

// ---------------- host launch ----------------
extern "C" void kernel_launch(void* const* d_in, const int* in_sizes, int n_in,
                              void* d_out, int out_size, void* d_ws, size_t ws_size,
                              hipStream_t stream) {
  const float* x     = (const float*)d_in[0];  // (16,1024,256)
  const float* adj   = (const float*)d_in[1];  // (1024,1024)
  const float* Wg    = (const float*)d_in[2];  // (256,256)
  const float* bg    = (const float*)d_in[3];  // (256,)
  const float* Wpre  = (const float*)d_in[4];  // (8,256)
  const float* bpre  = (const float*)d_in[5];  // (8,)
  const float* qw    = (const float*)d_in[6];  // (2,8)
  const float* Wpost = (const float*)d_in[7];  // (256,8)
  const float* bpost = (const float*)d_in[8];  // (256,)
  float* out = (float*)d_out;                  // (16,1024,256)

  char* ws = (char*)d_ws;
  unsigned short* adj_bf  = (unsigned short*)(ws + 0);          // 2 MiB
  unsigned short* Wg_bf   = (unsigned short*)(ws + 2097152);    // 128 KiB
  unsigned short* xagg_bf = (unsigned short*)(ws + 2228224);    // 8 MiB  (16384 x 256)
  unsigned short* xT_bf   = (unsigned short*)(ws + 10616832);   // 8 MiB  (16 x 256 x 1024)
  float*          gbuf    = (float*)(ws + 19005440);            // 16 MiB (16384 x 256)

  // 1) converts
  cvt_bf16_kernel<<<1024, 256, 0, stream>>>(adj, adj_bf, 1024 * 1024 / 4);
  cvt_bf16_kernel<<<64, 256, 0, stream>>>(Wg, Wg_bf, 256 * 256 / 4);
  transpose_cvt_kernel<<<dim3(32, 8, 16), dim3(32, 8), 0, stream>>>(x, xT_bf);

  // 2) x_agg[b] = adj @ x[b]  -> bf16 (16384 x 256)
  gemm_bt_kernel<0><<<256, 256, 0, stream>>>(adj_bf, xT_bf, (void*)xagg_bf, nullptr,
                                             1024, 8, 2,
                                             0LL, 262144LL, 262144LL, 256);

  // 3) g = gelu(x_agg @ Wg^T + bg)  -> fp32 (16384 x 256)
  gemm_bt_kernel<1><<<256, 256, 0, stream>>>(xagg_bf, Wg_bf, (void*)gbuf, bg,
                                             256, 128, 2,
                                             0LL, 0LL, 0LL, 256);

  // 4) fused angles + circuit + output projection
  qcircuit_kernel<<<4096, 256, 0, stream>>>(gbuf, Wpre, bpre, qw, Wpost, bpost, out);
}

// Round 2
// 167.135 us; speedup vs baseline: 1.1459x; 1.1459x over previous
//
#include <hip/hip_runtime.h>
#include <math.h>

typedef __attribute__((ext_vector_type(8))) short bf16x8;
typedef __attribute__((ext_vector_type(4))) float f32x4;

#define PI_F 3.14159265358979323846f

__device__ __forceinline__ unsigned short f2bf(float f) {
  unsigned int u = __float_as_uint(f);
  u += 0x7FFFu + ((u >> 16) & 1u);   // RNE to bf16
  return (unsigned short)(u >> 16);
}

__device__ __forceinline__ void async_ld16(const unsigned short* g, unsigned short* l) {
  __builtin_amdgcn_global_load_lds(
      (const __attribute__((address_space(1))) void*)g,
      (__attribute__((address_space(3))) void*)l,
      16, 0, 0);
}

// ---------------- fp32 -> bf16 convert: adj (1M elems) + Wg (64K elems) in one launch ----
__global__ __launch_bounds__(256)
void cvt_bf16_kernel(const float* __restrict__ s0, unsigned short* __restrict__ d0, int n40,
                     const float* __restrict__ s1, unsigned short* __restrict__ d1, int n41) {
  int i = blockIdx.x * 256 + threadIdx.x;
  const float* s; unsigned short* d;
  if (i < n40) { s = s0; d = d0; }
  else { i -= n40; if (i >= n41) return; s = s1; d = d1; }
  float4 v = ((const float4*)s)[i];
  ushort4 o;
  o.x = f2bf(v.x); o.y = f2bf(v.y); o.z = f2bf(v.z); o.w = f2bf(v.w);
  ((ushort4*)d)[i] = o;
}

// ---------------- transpose + convert: x (16,1024,256) -> xT (16,256,1024) bf16 ----------------
__global__ __launch_bounds__(256)
void transpose_cvt_kernel(const float* __restrict__ x, unsigned short* __restrict__ xT) {
  __shared__ float tile[32][33];
  int jt = blockIdx.x;   // 0..31  (1024/32)
  int ht = blockIdx.y;   // 0..7   (256/32)
  int b  = blockIdx.z;   // 0..15
  int tx = threadIdx.x;  // 0..31
  int ty = threadIdx.y;  // 0..7
  const float* xb = x + (size_t)b * 1024 * 256;
  #pragma unroll
  for (int i = 0; i < 4; i++) {
    int j = jt * 32 + ty + i * 8;
    tile[ty + i * 8][tx] = xb[(size_t)j * 256 + ht * 32 + tx];
  }
  __syncthreads();
  unsigned short* xTb = xT + (size_t)b * 256 * 1024;
  #pragma unroll
  for (int i = 0; i < 4; i++) {
    int h = ht * 32 + ty + i * 8;
    xTb[(size_t)h * 1024 + jt * 32 + tx] = f2bf(tile[tx][ty + i * 8]);
  }
}

// ---------------- MFMA GEMM, C = A * Bt^T  (A: MxK row-major bf16, Bt: NxK row-major bf16) ----
// MODE 0: store bf16 C.  MODE 1: bias + exact GELU, store fp32 C.
template<int MODE>
__global__ __launch_bounds__(256)
void gemm_bt_kernel(const unsigned short* __restrict__ A,
                    const unsigned short* __restrict__ Bt,
                    void* __restrict__ C,
                    const float* __restrict__ bias,
                    int K, int tilesM, int tilesN,
                    long long strideA, long long strideBt, long long strideC, int ldC) {
  __shared__ unsigned short As[128 * 32];
  __shared__ unsigned short Bs[128 * 32];
  int tiles = tilesM * tilesN;
  int b   = blockIdx.x / tiles;
  int rr  = blockIdx.x % tiles;
  int im  = rr / tilesN;
  int in_ = rr % tilesN;
  const unsigned short* Ab  = A  + (long long)b * strideA  + (long long)im * 128 * K;
  const unsigned short* Btb = Bt + (long long)b * strideBt + (long long)in_ * 128 * K;

  int t = threadIdx.x;
  int wv = t >> 6, lane = t & 63;
  int wm = wv >> 1, wn = wv & 1;
  int l15 = lane & 15, quad = lane >> 4;
  int row0 = t >> 2, cg = t & 3;

  f32x4 acc[4][4] = {};

  for (int kk = 0; kk < K; kk += 32) {
    __syncthreads();
    #pragma unroll
    for (int q = 0; q < 2; q++) {
      int row = row0 + q * 64;
      const unsigned short* ga = Ab  + (long long)row * K + kk + cg * 8;
      const unsigned short* gb = Btb + (long long)row * K + kk + cg * 8;
      unsigned short* la = &As[(wv * 64 + q * 256) * 8];
      unsigned short* lb = &Bs[(wv * 64 + q * 256) * 8];
      async_ld16(ga, la);
      async_ld16(gb, lb);
    }
    __syncthreads();
    bf16x8 af[4], bfr[4];
    #pragma unroll
    for (int mt = 0; mt < 4; mt++)
      af[mt] = *(const bf16x8*)&As[(wm * 64 + mt * 16 + l15) * 32 + quad * 8];
    #pragma unroll
    for (int nt = 0; nt < 4; nt++)
      bfr[nt] = *(const bf16x8*)&Bs[(wn * 64 + nt * 16 + l15) * 32 + quad * 8];
    #pragma unroll
    for (int mt = 0; mt < 4; mt++)
      #pragma unroll
      for (int nt = 0; nt < 4; nt++)
        acc[mt][nt] = __builtin_amdgcn_mfma_f32_16x16x32_bf16(af[mt], bfr[nt], acc[mt][nt], 0, 0, 0);
  }

  unsigned short* Cb_bf = (unsigned short*)C + (long long)b * strideC;
  float*          Cb_f  = (float*)C          + (long long)b * strideC;
  int n0 = in_ * 128;
  #pragma unroll
  for (int mt = 0; mt < 4; mt++) {
    #pragma unroll
    for (int nt = 0; nt < 4; nt++) {
      int colg = n0 + wn * 64 + nt * 16 + l15;
      #pragma unroll
      for (int r = 0; r < 4; r++) {
        long long rowg = (long long)im * 128 + wm * 64 + mt * 16 + quad * 4 + r;
        float v = acc[mt][nt][r];
        if (MODE == 0) {
          Cb_bf[rowg * ldC + colg] = f2bf(v);
        } else {
          v += bias[colg];
          v = 0.5f * v * (1.0f + erff(v * 0.7071067811865475f));
          Cb_f[rowg * ldC + colg] = v;
        }
      }
    }
  }
}

// ---------------- fused: angles -> 8-qubit circuit -> <Z> -> Wpost epilogue ----------------
// one sample per wave; 256 amplitudes = 4 complex per lane.
// stored amp index k: bits 0..5 = lane L, bits 6..7 = register r (k = r*64 + L).
// CNOT rings are DEFERRED: they are linear maps on the index bits; we track the
// stored->logical map F. Ring R (CNOT(0,1)..CNOT(7,0)):
//   layer-2 RX pair masks = R^-1 e_w = {03,06,0C,18,30,60,C0,83}
//   measurement sign masks = rows of R^2 = {AB,FD,FA,F5,EA,D5,AA,55}
// RX matrix is symmetric, so the XOR-pair update formula is identical for both halves.
template<int ML, int MR>
__device__ __forceinline__ void apply_rx(float re[4], float im[4], float c, float s) {
  float pr[4], pi[4];
  #pragma unroll
  for (int r = 0; r < 4; r++) {
    float vr = re[r ^ MR], vi = im[r ^ MR];
    if (ML) { vr = __shfl_xor(vr, ML, 64); vi = __shfl_xor(vi, ML, 64); }
    pr[r] = vr; pi[r] = vi;
  }
  #pragma unroll
  for (int r = 0; r < 4; r++) {
    re[r] = fmaf(c, re[r],  s * pi[r]);
    im[r] = fmaf(c, im[r], -s * pr[r]);
  }
}

// fold-reduce 8 values across 64 lanes: 10 shuffles. On exit v[0] of lane L holds
// the full wave-sum of value w(L) = 4*(L&1) + (L&2) + ((L>>2)&1).
__device__ __forceinline__ void fold_reduce8(float v[8], int L) {
  #pragma unroll
  for (int step = 0; step < 3; step++) {
    int d = 1 << step;
    int half = 4 >> step;
    bool hi = (L & d) != 0;
    #pragma unroll
    for (int w = 0; w < half; w++) {
      float send = hi ? v[w] : v[w + half];
      float recv = __shfl_xor(send, d, 64);
      v[w] = (hi ? v[w + half] : v[w]) + recv;
    }
  }
  v[0] += __shfl_xor(v[0], 8, 64);
  v[0] += __shfl_xor(v[0], 16, 64);
  v[0] += __shfl_xor(v[0], 32, 64);
}

__device__ __forceinline__ float fast_tanh(float a) {
  float e = __expf(2.0f * a);
  return 1.0f - 2.0f / (e + 1.0f);
}

__global__ __launch_bounds__(256)
void qcircuit_kernel(const float* __restrict__ g,
                     const float* __restrict__ Wpre, const float* __restrict__ bpre,
                     const float* __restrict__ qw,
                     const float* __restrict__ Wpost, const float* __restrict__ bpost,
                     float* __restrict__ out) {
  __shared__ float sWpre[2048];    // [w][h]  8x256 (native layout)
  __shared__ float sWpostT[2048];  // [w][h]  256x8 transposed -> conflict-free reads
  __shared__ float sBpost[256];
  int t = threadIdx.x;
  for (int i = t; i < 2048; i += 256) {
    sWpre[i] = Wpre[i];
    sWpostT[i] = Wpost[(i & 255) * 8 + (i >> 8)];
  }
  sBpost[t] = bpost[t];
  __syncthreads();

  int wv = t >> 6, L = t & 63;
  long long s = (long long)blockIdx.x * 4 + wv;
  const float* gr = g + s * 256;

  float gv[4];
  #pragma unroll
  for (int j = 0; j < 4; j++) gv[j] = gr[L + 64 * j];

  // angles: a_w = dot(g, Wpre[w]) ; partial per lane then fold-reduce
  float ang[8];
  #pragma unroll
  for (int w = 0; w < 8; w++) ang[w] = 0.f;
  #pragma unroll
  for (int j = 0; j < 4; j++)
    #pragma unroll
    for (int w = 0; w < 8; w++)
      ang[w] = fmaf(gv[j], sWpre[w * 256 + L + 64 * j], ang[w]);
  fold_reduce8(ang, L);
  float angf[8];
  #pragma unroll
  for (int w = 0; w < 8; w++) {
    int src = ((w >> 2) & 1) | ((w & 2)) | ((w & 1) << 2);
    angf[w] = __shfl(ang[0], src, 64);
  }

  // half-angle cos/sin of RY embedding: th = (pi/2)*tanh(a + bpre)
  float cw[8], sw[8];
  #pragma unroll
  for (int w = 0; w < 8; w++) {
    float th = (0.5f * PI_F) * fast_tanh(angf[w] + bpre[w]);
    cw[w] = __cosf(th); sw[w] = __sinf(th);
  }

  // product state after RY embedding
  float pl = 1.f;
  #pragma unroll
  for (int w = 0; w < 6; w++) pl *= ((L >> w) & 1) ? sw[w] : cw[w];
  float re[4], im[4];
  re[0] = pl * cw[6] * cw[7]; re[1] = pl * sw[6] * cw[7];
  re[2] = pl * cw[6] * sw[7]; re[3] = pl * sw[6] * sw[7];
  #pragma unroll
  for (int r = 0; r < 4; r++) im[r] = 0.f;

  // ---- layer 1 RX (F = I): masks e_w ----
  {
    float c[8], sn[8];
    #pragma unroll
    for (int w = 0; w < 8; w++) {
      float hh = 0.5f * qw[w];
      c[w] = __cosf(hh); sn[w] = __sinf(hh);
    }
    apply_rx<1, 0>(re, im, c[0], sn[0]);
    apply_rx<2, 0>(re, im, c[1], sn[1]);
    apply_rx<4, 0>(re, im, c[2], sn[2]);
    apply_rx<8, 0>(re, im, c[3], sn[3]);
    apply_rx<16, 0>(re, im, c[4], sn[4]);
    apply_rx<32, 0>(re, im, c[5], sn[5]);
    apply_rx<0, 1>(re, im, c[6], sn[6]);
    apply_rx<0, 2>(re, im, c[7], sn[7]);
  }
  // (ring CNOT 1 deferred: F = R)

  // ---- layer 2 RX (F = R): masks R^-1 e_w ----
  {
    float c[8], sn[8];
    #pragma unroll
    for (int w = 0; w < 8; w++) {
      float hh = 0.5f * qw[8 + w];
      c[w] = __cosf(hh); sn[w] = __sinf(hh);
    }
    apply_rx<3, 0>(re, im, c[0], sn[0]);    // 0x03
    apply_rx<6, 0>(re, im, c[1], sn[1]);    // 0x06
    apply_rx<12, 0>(re, im, c[2], sn[2]);   // 0x0C
    apply_rx<24, 0>(re, im, c[3], sn[3]);   // 0x18
    apply_rx<48, 0>(re, im, c[4], sn[4]);   // 0x30
    apply_rx<32, 1>(re, im, c[5], sn[5]);   // 0x60
    apply_rx<0, 3>(re, im, c[6], sn[6]);    // 0xC0 (register-local!)
    apply_rx<3, 2>(re, im, c[7], sn[7]);    // 0x83
  }
  // (ring CNOT 2 deferred: F = R^2)

  // ---- measure <Z_w> with sign masks = rows of R^2 ----
  float p0 = re[0] * re[0] + im[0] * im[0];
  float p1 = re[1] * re[1] + im[1] * im[1];
  float p2 = re[2] * re[2] + im[2] * im[2];
  float p3 = re[3] * re[3] + im[3] * im[3];
  float q1 = p0 - p1 + p2 - p3;   // reg-parity r&1
  float q2 = p0 + p1 - p2 - p3;   // reg-parity r&2
  float q3 = p0 - p1 - p2 + p3;   // reg-parity r&3
  float q0 = p0 + p1 + p2 + p3;
  (void)q0;
  float z[8];
  z[0] = (__popc(L & 0x2B) & 1) ? -q2 : q2;  // row 0xAB
  z[1] = (__popc(L & 0x3D) & 1) ? -q3 : q3;  // row 0xFD
  z[2] = (__popc(L & 0x3A) & 1) ? -q3 : q3;  // row 0xFA
  z[3] = (__popc(L & 0x35) & 1) ? -q3 : q3;  // row 0xF5
  z[4] = (__popc(L & 0x2A) & 1) ? -q3 : q3;  // row 0xEA
  z[5] = (__popc(L & 0x15) & 1) ? -q3 : q3;  // row 0xD5
  z[6] = (__popc(L & 0x2A) & 1) ? -q2 : q2;  // row 0xAA
  z[7] = (__popc(L & 0x15) & 1) ? -q1 : q1;  // row 0x55
  fold_reduce8(z, L);
  float zf[8];
  #pragma unroll
  for (int w = 0; w < 8; w++) {
    int src = ((w >> 2) & 1) | ((w & 2)) | ((w & 1) << 2);
    zf[w] = __shfl(z[0], src, 64);
  }

  // out = z @ Wpost^T + bpost   (conflict-free: [w][h] layout, consecutive lanes->banks)
  float* orow = out + s * 256;
  #pragma unroll
  for (int j = 0; j < 4; j++) {
    int hcol = L + 64 * j;
    float v = sBpost[hcol];
    #pragma unroll
    for (int w = 0; w < 8; w++) v = fmaf(zf[w], sWpostT[w * 256 + hcol], v);
    orow[hcol] = v;
  }
}

// ---------------- host launch ----------------
extern "C" void kernel_launch(void* const* d_in, const int* in_sizes, int n_in,
                              void* d_out, int out_size, void* d_ws, size_t ws_size,
                              hipStream_t stream) {
  const float* x     = (const float*)d_in[0];  // (16,1024,256)
  const float* adj   = (const float*)d_in[1];  // (1024,1024)
  const float* Wg    = (const float*)d_in[2];  // (256,256)
  const float* bg    = (const float*)d_in[3];  // (256,)
  const float* Wpre  = (const float*)d_in[4];  // (8,256)
  const float* bpre  = (const float*)d_in[5];  // (8,)
  const float* qw    = (const float*)d_in[6];  // (2,8)
  const float* Wpost = (const float*)d_in[7];  // (256,8)
  const float* bpost = (const float*)d_in[8];  // (256,)
  float* out = (float*)d_out;                  // (16,1024,256)

  char* ws = (char*)d_ws;
  unsigned short* adj_bf  = (unsigned short*)(ws + 0);          // 2 MiB
  unsigned short* Wg_bf   = (unsigned short*)(ws + 2097152);    // 128 KiB
  unsigned short* xagg_bf = (unsigned short*)(ws + 2228224);    // 8 MiB  (16384 x 256)
  unsigned short* xT_bf   = (unsigned short*)(ws + 10616832);   // 8 MiB  (16 x 256 x 1024)
  float*          gbuf    = (float*)(ws + 19005440);            // 16 MiB (16384 x 256)

  // 1) converts (adj + Wg fused into one launch) and x transpose
  cvt_bf16_kernel<<<1088, 256, 0, stream>>>(adj, adj_bf, 1024 * 1024 / 4,
                                            Wg, Wg_bf, 256 * 256 / 4);
  transpose_cvt_kernel<<<dim3(32, 8, 16), dim3(32, 8), 0, stream>>>(x, xT_bf);

  // 2) x_agg[b] = adj @ x[b]  -> bf16 (16384 x 256)
  gemm_bt_kernel<0><<<256, 256, 0, stream>>>(adj_bf, xT_bf, (void*)xagg_bf, nullptr,
                                             1024, 8, 2,
                                             0LL, 262144LL, 262144LL, 256);

  // 3) g = gelu(x_agg @ Wg^T + bg)  -> fp32 (16384 x 256)
  gemm_bt_kernel<1><<<256, 256, 0, stream>>>(xagg_bf, Wg_bf, (void*)gbuf, bg,
                                             256, 128, 2,
                                             0LL, 0LL, 0LL, 256);

  // 4) fused angles + circuit + output projection
  qcircuit_kernel<<<4096, 256, 0, stream>>>(gbuf, Wpre, bpre, qw, Wpost, bpost, out);
}

// Round 3
// 157.401 us; speedup vs baseline: 1.2168x; 1.0618x over previous
//
#include <hip/hip_runtime.h>
#include <math.h>

typedef __attribute__((ext_vector_type(8))) short bf16x8;
typedef __attribute__((ext_vector_type(4))) float f32x4;

#define PI_F 3.14159265358979323846f

__device__ __forceinline__ unsigned short f2bf(float f) {
  unsigned int u = __float_as_uint(f);
  u += 0x7FFFu + ((u >> 16) & 1u);   // RNE to bf16
  return (unsigned short)(u >> 16);
}

__device__ __forceinline__ void async_ld16(const unsigned short* g, unsigned short* l) {
  __builtin_amdgcn_global_load_lds(
      (const __attribute__((address_space(1))) void*)g,
      (__attribute__((address_space(3))) void*)l,
      16, 0, 0);
}

// fast erf, A&S 7.1.26, |err| <= 1.5e-7 absolute
__device__ __forceinline__ float fast_erf(float x) {
  float a = fabsf(x);
  float t = 1.0f / fmaf(0.3275911f, a, 1.0f);
  float p = t * fmaf(t, fmaf(t, fmaf(t, fmaf(t, 1.061405429f, -1.453152027f),
                                     1.421413741f), -0.284496736f), 0.254829592f);
  float e = __expf(-a * a);
  float r = 1.0f - p * e;
  return copysignf(r, x);
}

// ---------------- fp32 -> bf16 convert (adj + Wg) + gate cos/sin precompute ----
__global__ __launch_bounds__(256)
void cvt_bf16_kernel(const float* __restrict__ s0, unsigned short* __restrict__ d0, int n40,
                     const float* __restrict__ s1, unsigned short* __restrict__ d1, int n41,
                     const float* __restrict__ qw, float* __restrict__ gcs) {
  int gi = blockIdx.x * 256 + threadIdx.x;
  if (gi < n40) {
    float4 v = ((const float4*)s0)[gi];
    ushort4 o; o.x = f2bf(v.x); o.y = f2bf(v.y); o.z = f2bf(v.z); o.w = f2bf(v.w);
    ((ushort4*)d0)[gi] = o;
  } else if (gi < n40 + n41) {
    int i = gi - n40;
    float4 v = ((const float4*)s1)[i];
    ushort4 o; o.x = f2bf(v.x); o.y = f2bf(v.y); o.z = f2bf(v.z); o.w = f2bf(v.w);
    ((ushort4*)d1)[i] = o;
  } else {
    int w = gi - (n40 + n41);
    if (w < 16) {
      float hh = 0.5f * qw[w];
      gcs[w] = cosf(hh);
      gcs[16 + w] = sinf(hh);
    }
  }
}

// ---------------- transpose + convert: x (16,1024,256) -> xT (16,256,1024) bf16 ----------------
__global__ __launch_bounds__(256)
void transpose_cvt_kernel(const float* __restrict__ x, unsigned short* __restrict__ xT) {
  __shared__ float tile[32][33];
  int jt = blockIdx.x;   // 0..31
  int ht = blockIdx.y;   // 0..7
  int b  = blockIdx.z;   // 0..15
  int tx = threadIdx.x;  // 0..31
  int ty = threadIdx.y;  // 0..7
  const float* xb = x + (size_t)b * 1024 * 256;
  #pragma unroll
  for (int i = 0; i < 4; i++) {
    int j = jt * 32 + ty + i * 8;
    tile[ty + i * 8][tx] = xb[(size_t)j * 256 + ht * 32 + tx];
  }
  __syncthreads();
  unsigned short* xTb = xT + (size_t)b * 256 * 1024;
  #pragma unroll
  for (int i = 0; i < 4; i++) {
    int h = ht * 32 + ty + i * 8;
    xTb[(size_t)h * 1024 + jt * 32 + tx] = f2bf(tile[tx][ty + i * 8]);
  }
}

// ---------------- MFMA GEMM, C = A * Bt^T, tile 128(M) x 64(N) x 32(K) ----
// A: MxK row-major bf16; Bt: NxK row-major bf16.
// MODE 0: store bf16 C.  MODE 1: bias + GELU(erf), store fp32 C.
template<int MODE>
__global__ __launch_bounds__(256)
void gemm_bt_kernel(const unsigned short* __restrict__ A,
                    const unsigned short* __restrict__ Bt,
                    void* __restrict__ C,
                    const float* __restrict__ bias,
                    int K, int tilesM, int tilesN,
                    long long strideA, long long strideBt, long long strideC, int ldC) {
  __shared__ unsigned short As[128 * 32];
  __shared__ unsigned short Bs[64 * 32];
  int tiles = tilesM * tilesN;
  int b   = blockIdx.x / tiles;
  int rr  = blockIdx.x % tiles;
  int im  = rr / tilesN;
  int in_ = rr % tilesN;
  const unsigned short* Ab  = A  + (long long)b * strideA  + (long long)im * 128 * K;
  const unsigned short* Btb = Bt + (long long)b * strideBt + (long long)in_ * 64 * K;

  int t = threadIdx.x;
  int wv = t >> 6, lane = t & 63;
  int wm = wv >> 1, wn = wv & 1;          // wave grid 2(M) x 2(N)
  int l15 = lane & 15, quad = lane >> 4;
  int row0 = t >> 2, cg = t & 3;          // staging: 4 lanes/row, 8 bf16 each

  f32x4 acc[4][2] = {};

  for (int kk = 0; kk < K; kk += 32) {
    __syncthreads();
    // A: 128 rows x 32 cols, two rounds of 64 rows
    #pragma unroll
    for (int q = 0; q < 2; q++) {
      int row = row0 + q * 64;
      async_ld16(Ab + (long long)row * K + kk + cg * 8,
                 &As[(wv * 16 + q * 64) * 32]);
    }
    // B: 64 rows x 32 cols, one round
    async_ld16(Btb + (long long)row0 * K + kk + cg * 8,
               &Bs[wv * 16 * 32]);
    __syncthreads();
    bf16x8 af[4], bfr[2];
    #pragma unroll
    for (int mt = 0; mt < 4; mt++)
      af[mt] = *(const bf16x8*)&As[(wm * 64 + mt * 16 + l15) * 32 + quad * 8];
    #pragma unroll
    for (int nt = 0; nt < 2; nt++)
      bfr[nt] = *(const bf16x8*)&Bs[(wn * 32 + nt * 16 + l15) * 32 + quad * 8];
    #pragma unroll
    for (int mt = 0; mt < 4; mt++)
      #pragma unroll
      for (int nt = 0; nt < 2; nt++)
        acc[mt][nt] = __builtin_amdgcn_mfma_f32_16x16x32_bf16(af[mt], bfr[nt], acc[mt][nt], 0, 0, 0);
  }

  unsigned short* Cb_bf = (unsigned short*)C + (long long)b * strideC;
  float*          Cb_f  = (float*)C          + (long long)b * strideC;
  int n0 = in_ * 64;
  #pragma unroll
  for (int mt = 0; mt < 4; mt++) {
    #pragma unroll
    for (int nt = 0; nt < 2; nt++) {
      int colg = n0 + wn * 32 + nt * 16 + l15;
      #pragma unroll
      for (int r = 0; r < 4; r++) {
        long long rowg = (long long)im * 128 + wm * 64 + mt * 16 + quad * 4 + r;
        float v = acc[mt][nt][r];
        if (MODE == 0) {
          Cb_bf[rowg * ldC + colg] = f2bf(v);
        } else {
          v += bias[colg];
          v = 0.5f * v * (1.0f + fast_erf(v * 0.7071067811865475f));
          Cb_f[rowg * ldC + colg] = v;
        }
      }
    }
  }
}

// ---------------- fused: angles -> 8-qubit circuit -> <Z> -> Wpost epilogue ----------------
// one sample per wave; 256 amplitudes = 4 complex per lane.
// stored amp index k: bits 0..5 = lane L, bits 6..7 = register r.
// CNOT rings DEFERRED (linear maps on index bits):
//   layer-2 RX pair masks = R^-1 e_w = {03,06,0C,18,30,60,C0,83}
//   measurement sign masks = rows of R^2 = {AB,FD,FA,F5,EA,D5,AA,55}
template<int ML, int MR>
__device__ __forceinline__ void apply_rx(float re[4], float im[4], float c, float s) {
  float pr[4], pi[4];
  #pragma unroll
  for (int r = 0; r < 4; r++) {
    float vr = re[r ^ MR], vi = im[r ^ MR];
    if (ML) { vr = __shfl_xor(vr, ML, 64); vi = __shfl_xor(vi, ML, 64); }
    pr[r] = vr; pi[r] = vi;
  }
  #pragma unroll
  for (int r = 0; r < 4; r++) {
    re[r] = fmaf(c, re[r],  s * pi[r]);
    im[r] = fmaf(c, im[r], -s * pr[r]);
  }
}

// fold-reduce 8 values across 64 lanes: 10 shuffles. On exit v[0] of lane L holds
// the full wave-sum of value w(L) = 4*(L&1) + (L&2) + ((L>>2)&1).
__device__ __forceinline__ void fold_reduce8(float v[8], int L) {
  #pragma unroll
  for (int step = 0; step < 3; step++) {
    int d = 1 << step;
    int half = 4 >> step;
    bool hi = (L & d) != 0;
    #pragma unroll
    for (int w = 0; w < half; w++) {
      float send = hi ? v[w] : v[w + half];
      float recv = __shfl_xor(send, d, 64);
      v[w] = (hi ? v[w + half] : v[w]) + recv;
    }
  }
  v[0] += __shfl_xor(v[0], 8, 64);
  v[0] += __shfl_xor(v[0], 16, 64);
  v[0] += __shfl_xor(v[0], 32, 64);
}

__device__ __forceinline__ float fast_tanh(float a) {
  float e = __expf(2.0f * a);
  return 1.0f - 2.0f / (e + 1.0f);
}

__global__ __launch_bounds__(256)
void qcircuit_kernel(const float* __restrict__ g,
                     const float* __restrict__ Wpre, const float* __restrict__ bpre,
                     const float* __restrict__ gcs,
                     const float* __restrict__ Wpost, const float* __restrict__ bpost,
                     float* __restrict__ out) {
  __shared__ float sWpre[2048];    // [w][h]  8x256
  __shared__ float sWpostT[2048];  // [w][h]  transposed -> conflict-free b128 reads
  __shared__ float sBpost[256];
  int t = threadIdx.x;
  for (int i = t; i < 2048; i += 256) {
    sWpre[i] = Wpre[i];
    sWpostT[i] = Wpost[(i & 255) * 8 + (i >> 8)];
  }
  sBpost[t] = bpost[t];
  __syncthreads();

  int wv = t >> 6, L = t & 63;
  long long s = (long long)blockIdx.x * 4 + wv;

  // lane L handles elements 4L..4L+3 of the sample row (dwordx4)
  float4 gq = ((const float4*)(g + s * 256))[L];

  float ang[8];
  #pragma unroll
  for (int w = 0; w < 8; w++) {
    float4 wp = *(const float4*)&sWpre[w * 256 + 4 * L];
    float a = gq.x * wp.x;
    a = fmaf(gq.y, wp.y, a);
    a = fmaf(gq.z, wp.z, a);
    a = fmaf(gq.w, wp.w, a);
    ang[w] = a;
  }
  fold_reduce8(ang, L);
  float angf[8];
  #pragma unroll
  for (int w = 0; w < 8; w++) {
    int src = ((w >> 2) & 1) | ((w & 2)) | ((w & 1) << 2);
    angf[w] = __shfl(ang[0], src, 64);
  }

  // half-angle cos/sin of RY embedding: th = (pi/2)*tanh(a + bpre)
  float cw[8], sw[8];
  #pragma unroll
  for (int w = 0; w < 8; w++) {
    float th = (0.5f * PI_F) * fast_tanh(angf[w] + bpre[w]);
    cw[w] = __cosf(th); sw[w] = __sinf(th);
  }

  // product state after RY embedding
  float pl = 1.f;
  #pragma unroll
  for (int w = 0; w < 6; w++) pl *= ((L >> w) & 1) ? sw[w] : cw[w];
  float re[4], im[4];
  re[0] = pl * cw[6] * cw[7]; re[1] = pl * sw[6] * cw[7];
  re[2] = pl * cw[6] * sw[7]; re[3] = pl * sw[6] * sw[7];
  #pragma unroll
  for (int r = 0; r < 4; r++) im[r] = 0.f;

  // ---- layer 1 RX (F = I): masks e_w ----  (gate cos/sin precomputed: gcs[w], gcs[16+w])
  apply_rx<1, 0>(re, im, gcs[0], gcs[16]);
  apply_rx<2, 0>(re, im, gcs[1], gcs[17]);
  apply_rx<4, 0>(re, im, gcs[2], gcs[18]);
  apply_rx<8, 0>(re, im, gcs[3], gcs[19]);
  apply_rx<16, 0>(re, im, gcs[4], gcs[20]);
  apply_rx<32, 0>(re, im, gcs[5], gcs[21]);
  apply_rx<0, 1>(re, im, gcs[6], gcs[22]);
  apply_rx<0, 2>(re, im, gcs[7], gcs[23]);
  // ---- layer 2 RX (F = R): masks R^-1 e_w ----
  apply_rx<3, 0>(re, im, gcs[8], gcs[24]);    // 0x03
  apply_rx<6, 0>(re, im, gcs[9], gcs[25]);    // 0x06
  apply_rx<12, 0>(re, im, gcs[10], gcs[26]);  // 0x0C
  apply_rx<24, 0>(re, im, gcs[11], gcs[27]);  // 0x18
  apply_rx<48, 0>(re, im, gcs[12], gcs[28]);  // 0x30
  apply_rx<32, 1>(re, im, gcs[13], gcs[29]);  // 0x60
  apply_rx<0, 3>(re, im, gcs[14], gcs[30]);   // 0xC0 (register-local)
  apply_rx<3, 2>(re, im, gcs[15], gcs[31]);   // 0x83

  // ---- measure <Z_w> with sign masks = rows of R^2 ----
  float p0 = re[0] * re[0] + im[0] * im[0];
  float p1 = re[1] * re[1] + im[1] * im[1];
  float p2 = re[2] * re[2] + im[2] * im[2];
  float p3 = re[3] * re[3] + im[3] * im[3];
  float q1 = p0 - p1 + p2 - p3;   // reg-parity r&1
  float q2 = p0 + p1 - p2 - p3;   // reg-parity r&2
  float q3 = p0 - p1 - p2 + p3;   // reg-parity r&3
  float z[8];
  z[0] = (__popc(L & 0x2B) & 1) ? -q2 : q2;  // row 0xAB
  z[1] = (__popc(L & 0x3D) & 1) ? -q3 : q3;  // row 0xFD
  z[2] = (__popc(L & 0x3A) & 1) ? -q3 : q3;  // row 0xFA
  z[3] = (__popc(L & 0x35) & 1) ? -q3 : q3;  // row 0xF5
  z[4] = (__popc(L & 0x2A) & 1) ? -q3 : q3;  // row 0xEA
  z[5] = (__popc(L & 0x15) & 1) ? -q3 : q3;  // row 0xD5
  z[6] = (__popc(L & 0x2A) & 1) ? -q2 : q2;  // row 0xAA
  z[7] = (__popc(L & 0x15) & 1) ? -q1 : q1;  // row 0x55
  fold_reduce8(z, L);
  float zf[8];
  #pragma unroll
  for (int w = 0; w < 8; w++) {
    int src = ((w >> 2) & 1) | ((w & 2)) | ((w & 1) << 2);
    zf[w] = __shfl(z[0], src, 64);
  }

  // out = z @ Wpost^T + bpost ; lane L writes cols 4L..4L+3 (dwordx4)
  float4 v = *(const float4*)&sBpost[4 * L];
  #pragma unroll
  for (int w = 0; w < 8; w++) {
    float4 wp = *(const float4*)&sWpostT[w * 256 + 4 * L];
    v.x = fmaf(zf[w], wp.x, v.x);
    v.y = fmaf(zf[w], wp.y, v.y);
    v.z = fmaf(zf[w], wp.z, v.z);
    v.w = fmaf(zf[w], wp.w, v.w);
  }
  ((float4*)(out + s * 256))[L] = v;
}

// ---------------- host launch ----------------
extern "C" void kernel_launch(void* const* d_in, const int* in_sizes, int n_in,
                              void* d_out, int out_size, void* d_ws, size_t ws_size,
                              hipStream_t stream) {
  const float* x     = (const float*)d_in[0];  // (16,1024,256)
  const float* adj   = (const float*)d_in[1];  // (1024,1024)
  const float* Wg    = (const float*)d_in[2];  // (256,256)
  const float* bg    = (const float*)d_in[3];  // (256,)
  const float* Wpre  = (const float*)d_in[4];  // (8,256)
  const float* bpre  = (const float*)d_in[5];  // (8,)
  const float* qw    = (const float*)d_in[6];  // (2,8)
  const float* Wpost = (const float*)d_in[7];  // (256,8)
  const float* bpost = (const float*)d_in[8];  // (256,)
  float* out = (float*)d_out;                  // (16,1024,256)

  char* ws = (char*)d_ws;
  unsigned short* adj_bf  = (unsigned short*)(ws + 0);          // 2 MiB
  unsigned short* Wg_bf   = (unsigned short*)(ws + 2097152);    // 128 KiB
  unsigned short* xagg_bf = (unsigned short*)(ws + 2228224);    // 8 MiB  (16384 x 256)
  unsigned short* xT_bf   = (unsigned short*)(ws + 10616832);   // 8 MiB  (16 x 256 x 1024)
  float*          gbuf    = (float*)(ws + 19005440);            // 16 MiB (16384 x 256)
  float*          gcs     = (float*)(ws + 35782656);            // 128 B  (32 floats)

  // 1) converts (adj + Wg + gate table fused) and x transpose
  cvt_bf16_kernel<<<1089, 256, 0, stream>>>(adj, adj_bf, 1024 * 1024 / 4,
                                            Wg, Wg_bf, 256 * 256 / 4, qw, gcs);
  transpose_cvt_kernel<<<dim3(32, 8, 16), dim3(32, 8), 0, stream>>>(x, xT_bf);

  // 2) x_agg[b] = adj @ x[b]  -> bf16 (16384 x 256); tiles 8x4, 16 batches = 512 blocks
  gemm_bt_kernel<0><<<512, 256, 0, stream>>>(adj_bf, xT_bf, (void*)xagg_bf, nullptr,
                                             1024, 8, 4,
                                             0LL, 262144LL, 262144LL, 256);

  // 3) g = gelu(x_agg @ Wg^T + bg) -> fp32 (16384 x 256); tiles 128x4 = 512 blocks
  gemm_bt_kernel<1><<<512, 256, 0, stream>>>(xagg_bf, Wg_bf, (void*)gbuf, bg,
                                             256, 128, 4,
                                             0LL, 0LL, 0LL, 256);

  // 4) fused angles + circuit + output projection
  qcircuit_kernel<<<4096, 256, 0, stream>>>(gbuf, Wpre, bpre, gcs, Wpost, bpost, out);
}